// Round 2
// baseline (5107.398 us; speedup 1.0000x reference)
//
#include <hip/hip_runtime.h>

// Decoder GRU, B=128 T=512 X=64 H=256, skip runtime (1..7; skip==0 -> generic
// path).  Round 8: pair-split persistent RNN.
//
// R6/R7 post-mortem: both land at ~8000 cyc/step with VALUBusy 16% regardless
// of barrier structure.  Weights (480 KB fp16/WG) CANNOT be register-resident
// (512 KB regfile/CU total) -> compiler re-streams 491 KB/CU/step from L2 at
// ~62 B/cyc = the per-CU VMEM return BW.  That is the real roofline of the
// 1-WG-per-batch structure.
//
// This round: 256 WGs, a CU PAIR per batch (halves = gate-column split), so
// per-CU streamed weights drop to 240 KB/step; 96 KB of that is cached in LDS
// -> 147 KB/step streamed.  Halves exchange only their 128-col h (512 B fp32)
// per step via L2 + flag handshake (pair (g, g+128) -> same XCD round-robin
// slot).  Projection (depends only on h(i-1)) runs while waiting for the
// partner.  Double-buffered payload slots are race-free: publish(i) precedes
// consume(i), so a half can never be 2 steps ahead of its partner's reads.
// Cooperative launch guarantees co-residency (fallback: plain launch).
// LDS padded layouts (hid2 stride 40, pt2 stride 24 words) keep broadcast
// reads bank-conflict-free (fixes R7's 4.2e7 conflicts).
typedef _Float16 h2_t __attribute__((ext_vector_type(2)));

constexpr int T_ = 512;
constexpr int X_ = 64;
constexpr int H_ = 256;
constexpr int NPAIR = 128;  // batches
constexpr int NWG = 256;    // 2 WGs (halves) per batch
constexpr int NT = 512;
constexpr int RS = 16;      // ring slots; lookback 2*skip <= 14
constexpr int WU = 30;      // weight uint4 per thread (24 whh + 6 wih)
constexpr int CUT = 12;     // of which cached in LDS (96 KB)

// d_ws layout (uint4): [WHH2/WIH2: 2*30*512][WOUT: 4*512][PAY: 16384][FLG: 2048]
constexpr int GW_U4 = 2 * WU * 512;          // 30720
constexpr int GO_U4 = 4 * 512;               // 2048
constexpr int PAY_U4 = NPAIR * 2 * H_ / 4;   // 16384 (128 pairs x 2 slots x 256 f32)
constexpr int FLG_U4 = 2048;                 // flags padded to 64 B stride
constexpr int FSTR = 16;                     // flag stride in ints

__device__ __forceinline__ float sigmoid_f(float x) {
  float e = __expf(fminf(-x, 80.f));
  return 1.f / (1.f + e);
}
__device__ __forceinline__ float tanh_f(float x) {
  float e = __expf(fminf(-2.f * x, 80.f));
  return (1.f - e) / (1.f + e);
}

__device__ __forceinline__ unsigned pk2(float a, float b) {
  h2_t v;
  v[0] = (_Float16)a;
  v[1] = (_Float16)b;
  return __builtin_bit_cast(unsigned, v);
}
__device__ __forceinline__ uint4 pk8(const float* s) {
  return make_uint4(pk2(s[0], s[1]), pk2(s[2], s[3]), pk2(s[4], s[5]),
                    pk2(s[6], s[7]));
}

__device__ __forceinline__ float dotp(unsigned w, unsigned h, float acc) {
  h2_t wv = __builtin_bit_cast(h2_t, w);
  h2_t hv = __builtin_bit_cast(h2_t, h);
#if __has_builtin(__builtin_amdgcn_fdot2)
  return __builtin_amdgcn_fdot2(wv, hv, acc, false);
#else
  acc = fmaf((float)wv[0], (float)hv[0], acc);
  return fmaf((float)wv[1], (float)hv[1], acc);
#endif
}
__device__ __forceinline__ float dotq(uint4 w, uint4 h, float acc) {
  acc = dotp(w.x, h.x, acc);
  acc = dotp(w.y, h.y, acc);
  acc = dotp(w.z, h.z, acc);
  acc = dotp(w.w, h.w, acc);
  return acc;
}

// fp32 -> fp16 pack into per-(half,thread,u) stream layout; zero flags.
__global__ void prep_kernel(const float* __restrict__ Wih,
                            const float* __restrict__ Whh,
                            const float* __restrict__ Wout,
                            uint4* __restrict__ G) {
  int id = blockIdx.x * 256 + threadIdx.x;
  if (id < GW_U4) {
    int t = id & 511, r = id >> 9;  // r = h*30 + u
    int u = r % WU, h = r / WU;
    int c2 = t >> 2, kq = t & 3, c = h * 128 + c2;
    if (u < 24) {
      int g = u >> 3, j = u & 7;
      G[id] = pk8(Whh + (size_t)(g * H_ + c) * H_ + kq * 64 + j * 8);
    } else {
      int v = u - 24, g = v >> 1, j = v & 1;
      G[id] = pk8(Wih + (size_t)(g * H_ + c) * X_ + kq * 16 + j * 8);
    }
  } else if (id < GW_U4 + GO_U4) {
    int jd = id - GW_U4;
    int u = jd >> 9, t = jd & 511;
    int xc = t >> 3, sl = t & 7;
    G[id] = pk8(Wout + (size_t)xc * H_ + sl * 32 + u * 8);
  } else if (id < GW_U4 + GO_U4 + FLG_U4) {
    // zero flag region every dispatch (protocol restart)
    G[GW_U4 + GO_U4 + PAY_U4 + (id - GW_U4 - GO_U4)] = make_uint4(0, 0, 0, 0);
  }
}

// cached-or-streamed weight fetch (u must be compile-time after unroll)
#define FETCHW(u) ((u) < CUT ? wl[(u)*512 + t] : Gw[(size_t)(u) * 512])

// Own-half gates for col c: k-quarter per lane, 4-lane shfl reduce.
#define GATES_(p, hn)                                                        \
  float hn;                                                                  \
  {                                                                          \
    const uint4* h4 = (const uint4*)&hid2[p][kq * 40];                       \
    uint4 hv[8];                                                             \
    _Pragma("unroll") for (int j = 0; j < 8; ++j) hv[j] = h4[j];             \
    float r0 = 0, r1 = 0, z0 = 0, z1 = 0, n0 = 0, n1 = 0;                    \
    _Pragma("unroll") for (int j = 0; j < 8; j += 2) {                       \
      r0 = dotq(FETCHW(j), hv[j], r0);                                       \
      r1 = dotq(FETCHW(j + 1), hv[j + 1], r1);                               \
      z0 = dotq(FETCHW(8 + j), hv[j], z0);                                   \
      z1 = dotq(FETCHW(9 + j), hv[j + 1], z1);                               \
      n0 = dotq(FETCHW(16 + j), hv[j], n0);                                  \
      n1 = dotq(FETCHW(17 + j), hv[j + 1], n1);                              \
    }                                                                        \
    const uint4* x4 = (const uint4*)&xt2[p][kq * 8];                         \
    uint4 xv0 = x4[0], xv1 = x4[1];                                          \
    float ni = 0;                                                            \
    r0 = dotq(FETCHW(24), xv0, r0);                                          \
    r1 = dotq(FETCHW(25), xv1, r1);                                          \
    z0 = dotq(FETCHW(26), xv0, z0);                                          \
    z1 = dotq(FETCHW(27), xv1, z1);                                          \
    ni = dotq(FETCHW(28), xv0, ni);                                          \
    ni = dotq(FETCHW(29), xv1, ni);                                          \
    float ar = r0 + r1, az = z0 + z1, anh = n0 + n1;                         \
    ar += __shfl_xor(ar, 1);                                                 \
    ar += __shfl_xor(ar, 2);                                                 \
    az += __shfl_xor(az, 1);                                                 \
    az += __shfl_xor(az, 2);                                                 \
    anh += __shfl_xor(anh, 1);                                               \
    anh += __shfl_xor(anh, 2);                                               \
    ni += __shfl_xor(ni, 1);                                                 \
    ni += __shfl_xor(ni, 2);                                                 \
    float r = sigmoid_f(ar + bsr);                                           \
    float z = sigmoid_f(az + bsz);                                           \
    float n = tanh_f(ni + bin_ + r * (anh + bhn_));                          \
    hn = fmaf(z, hidf[p][c2] - n, n); /* (1-z)*n + z*hidden */               \
  }

// Full projection (redundant per half; only half 0 writes out).
#define PROJ_(p, q, i)                                                       \
  {                                                                          \
    const uint4* p4 = (const uint4*)&pt2[p][sl * 24];                        \
    float fa = 0;                                                            \
    fa = dotq(wout_r[0 * 512 + t], p4[0], fa);                               \
    fa = dotq(wout_r[1 * 512 + t], p4[1], fa);                               \
    fa = dotq(wout_r[2 * 512 + t], p4[2], fa);                               \
    fa = dotq(wout_r[3 * 512 + t], p4[3], fa);                               \
    fa += __shfl_xor(fa, 1);                                                 \
    fa += __shfl_xor(fa, 2);                                                 \
    fa += __shfl_xor(fa, 4);                                                 \
    float o = fa + bo;                                                       \
    if (sl == 0 && hwg == 0) out[ob + (size_t)(i)*X_ + xc] = o;              \
    float oo = __shfl_xor(o, 8);                                             \
    if ((t & 15) == 0) xt2[q][t >> 4] = pk2(o, oo);                          \
  }

#define PUBLISH_(i, hn)                                                      \
  if ((t & 3) == 0)                                                          \
    __hip_atomic_store(&pay[((size_t)pair * 2 + ((i)&1)) * H_ + c], hn,      \
                       __ATOMIC_RELAXED, __HIP_MEMORY_SCOPE_AGENT);          \
  __syncthreads();                                                           \
  if (t == 0)                                                                \
    __hip_atomic_store(&flg[(pair * 2 + hwg) * FSTR], (i) + 1,               \
                       __ATOMIC_RELEASE, __HIP_MEMORY_SCOPE_AGENT);

#define SPIN_(i)                                                             \
  while (__hip_atomic_load(&flg[(pair * 2 + (hwg ^ 1)) * FSTR],              \
                           __ATOMIC_ACQUIRE, __HIP_MEMORY_SCOPE_AGENT) <     \
         (i) + 1) {                                                          \
  }

__global__ __launch_bounds__(NT, 1) void decoder_kernel(
    const float* __restrict__ h_enc, const float* __restrict__ b_ih,
    const float* __restrict__ b_hh, const float* __restrict__ b_out,
    const int* __restrict__ mask0, const int* __restrict__ mask1,
    const int* __restrict__ skipp, const uint4* __restrict__ G,
    float* __restrict__ pay_, int* __restrict__ flg_,
    float* __restrict__ out) {
  __shared__ alignas(16) uint4 wl[CUT * 512];    // 96 KB weight cache
  __shared__ alignas(16) uint4 wout_r[4 * 512];  // 32 KB W_out fp16 [u][t]
  __shared__ float ring[RS][H_];                 // 16 KB full-h history (fp32)
  __shared__ alignas(16) unsigned hid2[2][160];  // fp16 hidden, 4 blk x 40 pad
  __shared__ alignas(16) unsigned pt2[2][192];   // fp16 h_prev+skip, 8 blk x 24
  __shared__ alignas(16) unsigned xt2[2][X_ / 2];  // fp16 x feedback
  __shared__ float hidf[2][128];                 // fp32 hidden, own half
  __shared__ float m0f[T_], m1f[T_];             // masks

  const int t = threadIdx.x;
  const int bid = blockIdx.x;
  const int pair = bid & (NPAIR - 1);  // batch
  const int hwg = bid >> 7;            // column half (pair partner = bid^128)
  const int c2 = t >> 2, kq = t & 3;   // gate role: local col, k-quarter
  const int c = hwg * 128 + c2;        // global gate column
  const int xc = t >> 3, sl = t & 7;   // projection role
  const size_t ob = (size_t)pair * T_ * X_;
  float* pay = pay_;
  int* flg = flg_;

  const uint4* Gw = G + (size_t)hwg * WU * 512 + t;  // streamed-weight base

  // ---- init ----
#pragma unroll
  for (int u = 0; u < CUT; ++u) wl[u * 512 + t] = Gw[(size_t)u * 512];
#pragma unroll
  for (int j = 0; j < 4; ++j) wout_r[j * 512 + t] = G[GW_U4 + j * 512 + t];
  m0f[t] = (float)mask0[t];
  m1f[t] = (float)mask1[t];

  const int skip = skipp[0];
  const int i0 = (skip == 0) ? T_ : ((2 * skip < T_) ? 2 * skip : T_);

  const float bsr = b_ih[c] + b_hh[c];
  const float bsz = b_ih[H_ + c] + b_hh[H_ + c];
  const float bin_ = b_ih[2 * H_ + c];
  const float bhn_ = b_hh[2 * H_ + c];
  const float bo = b_out[xc];

  if (t < 128) {
    int c0 = 2 * t;
    float h0 = h_enc[(size_t)pair * H_ + c0];
    float h1 = h_enc[(size_t)pair * H_ + c0 + 1];
    ring[RS - 1][c0] = h0;  // "h(-1)" = h_enc for prologue h_prev
    ring[RS - 1][c0 + 1] = h1;
    float m00 = (float)mask0[0];
    float g0 = m00 * h0, g1 = m00 * h1;  // hidden(0); skip_g(0) == 0
    hid2[0][(t >> 5) * 40 + (t & 31)] = pk2(g0, g1);
    if ((c0 >> 7) == hwg) {
      hidf[0][c0 & 127] = g0;
      hidf[0][(c0 + 1) & 127] = g1;
    }
  }
  if (t < X_ / 2) xt2[0][t] = 0u;  // GO token
  __syncthreads();

  // ---- prologue: generic steps for i < 2*skip (and all steps if skip==0) --
  for (int i = 0; i < i0; ++i) {
    const int p = i & 1, q = p ^ 1;
    GATES_(p, hn)
    PUBLISH_(i, hn)
    if (t < 128) {
      SPIN_(i)
      int c0 = 2 * t;
      size_t pb = ((size_t)pair * 2 + (i & 1)) * H_;
      float h0 = __hip_atomic_load(&pay[pb + c0], __ATOMIC_RELAXED,
                                   __HIP_MEMORY_SCOPE_AGENT);
      float h1 = __hip_atomic_load(&pay[pb + c0 + 1], __ATOMIC_RELAXED,
                                   __HIP_MEMORY_SCOPE_AGENT);
      ring[i & (RS - 1)][c0] = h0;
      ring[i & (RS - 1)][c0 + 1] = h1;
      // pt(i) for this step's projection (generic incl. pi==i self-ref)
      float hp0 = ring[(i - 1) & (RS - 1)][c0];
      float hp1 = ring[(i - 1) & (RS - 1)][c0 + 1];
      int ppos = (i < skip) ? 2 * i + 1 : i - skip;
      bool pz = ppos < skip;
      int pi = ppos - skip;
      if (pi < 0) pi = 0;
      float sp0 = pz ? 0.f : ((pi == i) ? h0 : ring[pi & (RS - 1)][c0]);
      float sp1 = pz ? 0.f : ((pi == i) ? h1 : ring[pi & (RS - 1)][c0 + 1]);
      pt2[p][(t >> 4) * 24 + (t & 15)] = pk2(hp0 + sp0, hp1 + sp1);
      int i1 = i + 1;
      if (i1 < T_) {
        int pg = (i1 < skip) ? 2 * i1 : i1 - skip;
        bool gz = pg < skip;
        int gi = pg - skip;
        if (gi < 0) gi = 0;
        if (gi >= i1) gz = true;  // unwritten slot == reference zero init
        float s0 = gz ? 0.f : ((gi == i) ? h0 : ring[gi & (RS - 1)][c0]);
        float s1 = gz ? 0.f : ((gi == i) ? h1 : ring[gi & (RS - 1)][c0 + 1]);
        float g0 = m0f[i1] * h0 + m1f[i1] * s0;
        float g1 = m0f[i1] * h1 + m1f[i1] * s1;
        hid2[q][(t >> 5) * 40 + (t & 31)] = pk2(g0, g1);
        if ((c0 >> 7) == hwg) {
          hidf[q][c0 & 127] = g0;
          hidf[q][(c0 + 1) & 127] = g1;
        }
        if (skip > 0 && i1 >= 2 * skip) {  // handoff: pt(i0) main formula
          float sm0 = ring[(i1 - 2 * skip) & (RS - 1)][c0];
          float sm1 = ring[(i1 - 2 * skip) & (RS - 1)][c0 + 1];
          pt2[q][(t >> 4) * 24 + (t & 15)] = pk2(h0 + sm0, h1 + sm1);
        }
      }
    }
    __syncthreads();
    PROJ_(p, q, i)
    __syncthreads();
  }

  // ---- main loop: i >= 2*skip.  pt(i) was produced at step i-1; projection
  // is independent of this step's gates and covers the partner-h latency. ----
#pragma unroll 1
  for (int i = i0; i < T_; ++i) {
    const int p = i & 1, q = p ^ 1;
    GATES_(p, hn)
    PUBLISH_(i, hn)
    PROJ_(p, q, i)
    if (t < 128) {
      SPIN_(i)
      int c0 = 2 * t;
      size_t pb = ((size_t)pair * 2 + (i & 1)) * H_;
      float h0 = __hip_atomic_load(&pay[pb + c0], __ATOMIC_RELAXED,
                                   __HIP_MEMORY_SCOPE_AGENT);
      float h1 = __hip_atomic_load(&pay[pb + c0 + 1], __ATOMIC_RELAXED,
                                   __HIP_MEMORY_SCOPE_AGENT);
      ring[i & (RS - 1)][c0] = h0;
      ring[i & (RS - 1)][c0 + 1] = h1;
      int i1 = i + 1;
      if (i1 < T_) {
        float s0 = ring[(i1 - 2 * skip) & (RS - 1)][c0];
        float s1 = ring[(i1 - 2 * skip) & (RS - 1)][c0 + 1];
        float m0v = m0f[i1], m1v = m1f[i1];
        float g0 = fmaf(m0v, h0, m1v * s0);
        float g1 = fmaf(m0v, h1, m1v * s1);
        hid2[q][(t >> 5) * 40 + (t & 31)] = pk2(g0, g1);
        pt2[q][(t >> 4) * 24 + (t & 15)] = pk2(h0 + s0, h1 + s1);
        if ((c0 >> 7) == hwg) {
          hidf[q][c0 & 127] = g0;
          hidf[q][(c0 + 1) & 127] = g1;
        }
      }
    }
    __syncthreads();
  }
}

extern "C" void kernel_launch(void* const* d_in, const int* in_sizes, int n_in,
                              void* d_out, int out_size, void* d_ws,
                              size_t ws_size, hipStream_t stream) {
  (void)in_sizes; (void)n_in; (void)out_size; (void)ws_size;
  // d_in[0] = input [B,T,X] — unused by the reference computation.
  const float* h_enc = (const float*)d_in[1];
  const float* W_ih = (const float*)d_in[2];
  const float* W_hh = (const float*)d_in[3];
  const float* b_ih = (const float*)d_in[4];
  const float* b_hh = (const float*)d_in[5];
  const float* W_out = (const float*)d_in[6];
  const float* b_out = (const float*)d_in[7];
  const int* mask0 = (const int*)d_in[8];
  const int* mask1 = (const int*)d_in[9];
  const int* skipp = (const int*)d_in[10];
  float* out = (float*)d_out;
  uint4* G = (uint4*)d_ws;
  float* pay = (float*)(G + GW_U4 + GO_U4);
  int* flg = (int*)(G + GW_U4 + GO_U4 + PAY_U4);

  // fills weight images AND zeroes the flag region (protocol restart per run)
  constexpr int PREP_IDS = GW_U4 + GO_U4 + FLG_U4;
  prep_kernel<<<dim3((PREP_IDS + 255) / 256), dim3(256), 0, stream>>>(
      W_ih, W_hh, W_out, G);

  void* args[] = {(void*)&h_enc, (void*)&b_ih, (void*)&b_hh, (void*)&b_out,
                  (void*)&mask0, (void*)&mask1, (void*)&skipp, (void*)&G,
                  (void*)&pay,   (void*)&flg,   (void*)&out};
  hipError_t ce = hipLaunchCooperativeKernel((const void*)decoder_kernel,
                                             dim3(NWG), dim3(NT), args, 0,
                                             stream);
  if (ce != hipSuccess) {
    (void)hipGetLastError();  // clear; fall back to plain launch (grid==256
                              // WGs at 1 WG/CU on 256 CUs -> co-resident)
    decoder_kernel<<<dim3(NWG), dim3(NT), 0, stream>>>(
        h_enc, b_ih, b_hh, b_out, mask0, mask1, skipp, G, pay, flg, out);
  }
}

// Round 4
// 1131.356 us; speedup vs baseline: 4.5144x; 4.5144x over previous
//
#include <hip/hip_runtime.h>

// Decoder GRU, B=128 T=512 X=64 H=256, skip runtime (skip==0 -> generic
// path).  Round 10 = Round 9 with the PIN4 macro-capture bug fixed
// ((w).w expanded the parameter into the member accessor).
//
// R6-R8 post-mortems: per-step floor is weight re-streaming, 480 KB/step/CU
// from L2 at ~60 B/cyc = 8000 cyc/step (VGPR_Count=128 shows the compiler
// rematerialized R6's 240-reg weight array).  R8's cross-CU split removed
// half the streaming but added ~7 us/step of fabric handshake latency
// (VALUBusy 7.8%, FETCH 43 MB) -> never again.
//
// This round keeps ONE WG per batch and makes ALL weights CU-resident:
//   - W_hh (384 KB) in REGISTERS: 48 uint4 = 192 VGPR/thread, force-pinned
//     with asm("" : "+v") so the compiler cannot rematerialize the loads
//     (rule-17).  192 + ~50 working set < 256 VGPR cap at 8 waves/CU.
//   - W_ih (96 KB) + W_out (32 KB) in LDS, per-thread-sliced [u][t] layout
//     (per-lane contiguous 16 B -> conflict-free ds_read_b128).
//   - ring/state/masks ~23 KB; LDS total 151.5 KB of 160.
// Per-step memory traffic: 256 B out-write.  Zero streamed weights.
// New floor ~= max(VALU 256 dot2 x 2 waves/SIMD x 2cyc ~= 1030 cyc,
// LDS ~130 KB / 128 B/cyc ~= 1050 cyc) per step.
// pt2 rows padded to 36 words so PROJ's 8 sl-address-groups hit disjoint
// bank quads (kills R7's 4.2e7 conflicts).  sched_barrier(0) between phases
// caps register liveness.  Structure otherwise = R7's verified 1-barrier
// MSTEP + 2-barrier prologue.
typedef _Float16 h2_t __attribute__((ext_vector_type(2)));

constexpr int T_ = 512;
constexpr int X_ = 64;
constexpr int H_ = 256;
constexpr int NWG = 128;  // 1 batch per WG
constexpr int NT = 512;   // 8 waves, 1 WG/CU
constexpr int RS = 16;    // ring slots; lookback 2*skip, OK for skip <= 7

// fp16 weight images in d_ws (uint4 units)
constexpr int GHH_U4 = 3 * 2 * 16 * 256;  // [g][kh][j][c]
constexpr int GIH_U4 = 3 * 2 * 4 * 256;   // [g][kh][j][c]
constexpr int GOUT_U4 = 2048;             // [u][t]  (t = xc*8+sl)
constexpr int G_TOTAL = GHH_U4 + GIH_U4 + GOUT_U4;

__device__ __forceinline__ float sigmoid_f(float x) {
  float e = __expf(fminf(-x, 80.f));
  return 1.f / (1.f + e);
}
__device__ __forceinline__ float tanh_f(float x) {
  float e = __expf(fminf(-2.f * x, 80.f));
  return (1.f - e) / (1.f + e);
}

__device__ __forceinline__ unsigned pk2(float a, float b) {
  h2_t v;
  v[0] = (_Float16)a;
  v[1] = (_Float16)b;
  return __builtin_bit_cast(unsigned, v);
}
__device__ __forceinline__ uint4 pk8(const float* s) {
  return make_uint4(pk2(s[0], s[1]), pk2(s[2], s[3]), pk2(s[4], s[5]),
                    pk2(s[6], s[7]));
}

// fp16-pair dot with fp32 accumulate (v_dot2_f32_f16)
__device__ __forceinline__ float dotp(unsigned w, unsigned h, float acc) {
  h2_t wv = __builtin_bit_cast(h2_t, w);
  h2_t hv = __builtin_bit_cast(h2_t, h);
#if __has_builtin(__builtin_amdgcn_fdot2)
  return __builtin_amdgcn_fdot2(wv, hv, acc, false);
#else
  acc = fmaf((float)wv[0], (float)hv[0], acc);
  return fmaf((float)wv[1], (float)hv[1], acc);
#endif
}
__device__ __forceinline__ float dotq(uint4 w, uint4 h, float acc) {
  acc = dotp(w.x, h.x, acc);
  acc = dotp(w.y, h.y, acc);
  acc = dotp(w.z, h.z, acc);
  acc = dotp(w.w, h.w, acc);
  return acc;
}

// One-time fp32 -> fp16 pack + transpose into register/LDS-friendly layouts.
__global__ void prep_kernel(const float* __restrict__ Wih,
                            const float* __restrict__ Whh,
                            const float* __restrict__ Wout,
                            uint4* __restrict__ G) {
  int id = blockIdx.x * 256 + threadIdx.x;
  if (id < GHH_U4) {
    int c = id & 255, r = id >> 8;
    int j = r & 15, gk = r >> 4, g = gk >> 1, kh = gk & 1;
    G[id] = pk8(Whh + (size_t)(g * 256 + c) * H_ + kh * 128 + j * 8);
  } else if (id < GHH_U4 + GIH_U4) {
    int jd = id - GHH_U4;
    int c = jd & 255, r = jd >> 8;
    int j = r & 3, gk = r >> 2, g = gk >> 1, kh = gk & 1;
    G[id] = pk8(Wih + (size_t)(g * 256 + c) * X_ + kh * 32 + j * 8);
  } else if (id < G_TOTAL) {
    int jd = id - GHH_U4 - GIH_U4;  // [0,2048): [u][t]
    int u = jd >> 9, tt = jd & 511;
    int xcp = tt >> 3, sl = tt & 7;
    G[id] = pk8(Wout + (size_t)xcp * H_ + sl * 32 + u * 8);
  }
}

// padded pt2 word index: row (cp>>4) stride 36 words -> the 8 sl-groups of
// PROJ start at banks 4*sl (disjoint quads), conflict-free.
#define PTW(cp) (((cp) >> 4) * 36 + ((cp)&15))

// NOTE: parameter name must not collide with the .x/.y/.z/.w member names.
#define PIN4(V4)                                                             \
  asm volatile("" : "+v"((V4).x), "+v"((V4).y), "+v"((V4).z), "+v"((V4).w))

// ---- per-step building blocks (p/q compile-time 0/1 in the main loop) ----

#define GATES(p, i, hn)                                                      \
  float hn;                                                                  \
  {                                                                          \
    float a0 = 0, a1 = 0, z0 = 0, z1 = 0, n0 = 0, n1 = 0, ni = 0;            \
    const uint4* h4 = ((const uint4*)hid2[p]) + kh * 16;                     \
    _Pragma("unroll") for (int j = 0; j < 16; j += 2) {                      \
      uint4 ha = h4[j], hb = h4[j + 1];                                      \
      a0 = dotq(whh[j], ha, a0);                                             \
      a1 = dotq(whh[j + 1], hb, a1);                                         \
      z0 = dotq(whh[16 + j], ha, z0);                                        \
      z1 = dotq(whh[17 + j], hb, z1);                                        \
      n0 = dotq(whh[32 + j], ha, n0);                                        \
      n1 = dotq(whh[33 + j], hb, n1);                                        \
    }                                                                        \
    const uint4* x4 = ((const uint4*)xt2[p]) + kh * 4;                       \
    _Pragma("unroll") for (int j = 0; j < 4; ++j) {                          \
      uint4 x8 = x4[j];                                                      \
      a0 = dotq(wlih[j * NT + t], x8, a0);                                   \
      z0 = dotq(wlih[(4 + j) * NT + t], x8, z0);                             \
      ni = dotq(wlih[(8 + j) * NT + t], x8, ni);                             \
    }                                                                        \
    float ar = a0 + a1, az = z0 + z1, anh = n0 + n1;                         \
    ar += __shfl_xor(ar, 1);                                                 \
    az += __shfl_xor(az, 1);                                                 \
    anh += __shfl_xor(anh, 1);                                               \
    ni += __shfl_xor(ni, 1);                                                 \
    float r = sigmoid_f(ar + bsr);                                           \
    float z = sigmoid_f(az + bsz);                                           \
    float n = tanh_f(ni + bin_ + r * (anh + bhn_));                          \
    hn = fmaf(z, hid_reg - n, n); /* (1-z)*n + z*hidden */                   \
    if (kh == 0) ring[(i) & (RS - 1)][c] = hn;                               \
  }

#define PROJ(p, q, i)                                                        \
  {                                                                          \
    float fa = 0;                                                            \
    const uint4* p4 = (const uint4*)&pt2[p][sl * 36];                        \
    _Pragma("unroll") for (int j = 0; j < 4; ++j) fa =                       \
        dotq(wout_r[j * NT + t], p4[j], fa);                                 \
    fa += __shfl_xor(fa, 1);                                                 \
    fa += __shfl_xor(fa, 2);                                                 \
    fa += __shfl_xor(fa, 4);                                                 \
    float o = fa + bo;                                                       \
    if (sl == 0) out[ob + (size_t)(i)*X_ + xc] = o;                          \
    float oo = __shfl_xor(o, 8);                                             \
    if ((t & 15) == 0) xt2[q][t >> 4] = pk2(o, oo);                          \
  }

// Main-loop step (valid for i >= 2*skip, skip >= 1): pt2[p] was produced at
// step i-1; sg == sp == h(i+1-2*skip) for the next step's hidden/pt.
#define MSTEP(i, p, q)                                                       \
  {                                                                          \
    GATES(p, i, hn)                                                          \
    __builtin_amdgcn_sched_barrier(0);                                       \
    PROJ(p, q, i)                                                            \
    __builtin_amdgcn_sched_barrier(0);                                       \
    if ((i) + 1 < T_) {                                                      \
      float sgp = ring[((i) + 1 - 2 * skip) & (RS - 1)][c];                  \
      float hidn = m0f[(i) + 1] * hn + m1f[(i) + 1] * sgp;                   \
      float ptn = hn + sgp;                                                  \
      hid_reg = hidn;                                                        \
      float ho = __shfl_xor(hidn, 2);                                        \
      float po = __shfl_xor(ptn, 2);                                         \
      if ((t & 3) == 0) {                                                    \
        hid2[q][t >> 2] = pk2(hidn, ho);                                     \
        pt2[q][PTW(t >> 2)] = pk2(ptn, po);                                  \
      }                                                                      \
    }                                                                        \
    __syncthreads();                                                         \
  }

__global__ __launch_bounds__(NT, 1) void decoder_kernel(
    const float* __restrict__ h_enc, const float* __restrict__ b_ih,
    const float* __restrict__ b_hh, const float* __restrict__ b_out,
    const int* __restrict__ mask0, const int* __restrict__ mask1,
    const int* __restrict__ skipp, const uint4* __restrict__ G,
    float* __restrict__ out) {
  __shared__ alignas(16) uint4 wlih[12 * NT];      // 96 KB W_ih fp16 [u][t]
  __shared__ alignas(16) uint4 wout_r[4 * NT];     // 32 KB W_out fp16 [u][t]
  __shared__ float ring[RS][H_];                   // 16 KB h history (fp32)
  __shared__ alignas(16) unsigned hid2[2][H_ / 2]; // fp16 hidden pairs
  __shared__ alignas(16) unsigned pt2[2][8 * 36];  // fp16 h_prev+skip, padded
  __shared__ alignas(16) unsigned xt2[2][X_ / 2];  // fp16 x feedback pairs
  __shared__ float m0f[T_], m1f[T_];               // 4 KB masks
  // total: 98304+32768+16384+1024+2304+256+4096 = 155136 B (151.5 KB)

  const int t = threadIdx.x;
  const int b = blockIdx.x;
  const int c = t >> 1, kh = t & 1;   // gate role: column, k-half
  const int xc = t >> 3, sl = t & 7;  // projection role
  const size_t ob = (size_t)b * T_ * X_;

  // ---- persistent W_hh registers (fp16 pairs), force-pinned ----
  uint4 whh[48];  // 3 gates x 16 uint4 (128 k each) = 192 VGPR
#pragma unroll
  for (int u = 0; u < 48; ++u)
    whh[u] = G[((u >> 4) * 32 + kh * 16 + (u & 15)) * 256 + c];
#pragma unroll
  for (int u = 0; u < 48; ++u) PIN4(whh[u]);  // no remat, no re-stream

  // ---- LDS weight caches ----
#pragma unroll
  for (int u = 0; u < 12; ++u)
    wlih[u * NT + t] = G[GHH_U4 + ((u >> 2) * 8 + kh * 4 + (u & 3)) * 256 + c];
#pragma unroll
  for (int j = 0; j < 4; ++j)
    wout_r[j * NT + t] = G[GHH_U4 + GIH_U4 + j * NT + t];
  m0f[t] = (float)mask0[t];
  m1f[t] = (float)mask1[t];

  const int skip = skipp[0];
  const int i0 = (skip == 0) ? T_ : ((2 * skip < T_) ? 2 * skip : T_);

  const float bsr = b_ih[c] + b_hh[c];
  const float bsz = b_ih[H_ + c] + b_hh[H_ + c];
  const float bin_ = b_ih[2 * H_ + c];
  const float bhn_ = b_hh[2 * H_ + c];
  const float bo = b_out[xc];

  float hp = h_enc[(size_t)b * H_ + c];
  float hid_reg = (float)mask0[0] * hp;  // hidden(0); skip_g(0) == 0
  float hps_reg = hp;                    // h_prev(0) = h_enc
  {
    float ho = __shfl_xor(hid_reg, 2);
    if ((t & 3) == 0) hid2[0][t >> 2] = pk2(hid_reg, ho);
  }
  if (t < X_ / 2) xt2[0][t] = 0u;  // GO token
  __syncthreads();

  // ---- prologue: generic 2-barrier steps for i < 2*skip ----
  for (int i = 0; i < i0; ++i) {
    const int p = i & 1, q = p ^ 1;
    GATES(p, i, hn)
    {
      int ppos = (i < skip) ? 2 * i + 1 : i - skip;
      bool pz = ppos < skip;
      int pi = ppos - skip;
      if (pi < 0) pi = 0;
      float sp = pz ? 0.f : ((pi == i) ? hn : ring[pi & (RS - 1)][c]);
      float ptv = hps_reg + sp;
      float po = __shfl_xor(ptv, 2);
      if ((t & 3) == 0) pt2[p][PTW(t >> 2)] = pk2(ptv, po);
    }
    if (i + 1 < T_) {
      int i1 = i + 1;
      int pg = (i1 < skip) ? 2 * i1 : i1 - skip;
      bool gz = pg < skip;
      int gi = pg - skip;
      if (gi < 0) gi = 0;
      if (gi >= i1) gz = true;  // unwritten slot == reference zero init
      float sg = gz ? 0.f : ((gi == i) ? hn : ring[gi & (RS - 1)][c]);
      float hidn = m0f[i1] * hn + m1f[i1] * sg;
      hid_reg = hidn;
      float ho = __shfl_xor(hidn, 2);
      if ((t & 3) == 0) hid2[q][t >> 2] = pk2(hidn, ho);
      if (skip > 0 && i1 >= 2 * skip) {  // handoff into fused main loop
        float sgp = ring[(i1 - 2 * skip) & (RS - 1)][c];
        float ptn = hn + sgp;
        float po2 = __shfl_xor(ptn, 2);
        if ((t & 3) == 0) pt2[q][PTW(t >> 2)] = pk2(ptn, po2);
      }
    }
    hps_reg = hn;
    __syncthreads();
    PROJ(p, q, i)
    __syncthreads();
  }

  // ---- main loop: one barrier per step; i0 even so parity is static ----
#pragma unroll 1
  for (int i = i0; i < T_; i += 2) {
    MSTEP(i, 0, 1)
    MSTEP(i + 1, 1, 0)
  }
}

extern "C" void kernel_launch(void* const* d_in, const int* in_sizes, int n_in,
                              void* d_out, int out_size, void* d_ws,
                              size_t ws_size, hipStream_t stream) {
  (void)in_sizes; (void)n_in; (void)out_size; (void)ws_size;
  // d_in[0] = input [B,T,X] — unused by the reference computation.
  const float* h_enc = (const float*)d_in[1];
  const float* W_ih = (const float*)d_in[2];
  const float* W_hh = (const float*)d_in[3];
  const float* b_ih = (const float*)d_in[4];
  const float* b_hh = (const float*)d_in[5];
  const float* W_out = (const float*)d_in[6];
  const float* b_out = (const float*)d_in[7];
  const int* mask0 = (const int*)d_in[8];
  const int* mask1 = (const int*)d_in[9];
  const int* skipp = (const int*)d_in[10];
  float* out = (float*)d_out;
  uint4* G = (uint4*)d_ws;  // 512 KB fp16 weight images

  prep_kernel<<<dim3(G_TOTAL / 256), dim3(256), 0, stream>>>(W_ih, W_hh,
                                                             W_out, G);
  decoder_kernel<<<dim3(NWG), dim3(NT), 0, stream>>>(
      h_enc, b_ih, b_hh, b_out, mask0, mask1, skipp, G, out);
}